// Round 7
// baseline (13759.496 us; speedup 1.0000x reference)
//
#include <hip/hip_runtime.h>

// Problem constants
#define Bn 128
#define Tn 512
#define Vn 128
#define En 64
#define Ln 128
#define Hn 512
#define G4 2048
#define WGS 256
#define NTHR 512
#define NALL (WGS * NTHR)
#define LSTR 520   // LDS row stride in u16 (16B-aligned rows)
#define GRPS 8
#define WPG 32     // WGs per group
#define RPG 16     // batch rows per group

typedef unsigned short u16;
typedef unsigned int u32;
typedef unsigned long long u64;
typedef __bf16 bf16x8 __attribute__((ext_vector_type(8)));
typedef float f32x4 __attribute__((ext_vector_type(4)));
typedef u32 u32x4 __attribute__((ext_vector_type(4)));
typedef u32 u32x2 __attribute__((ext_vector_type(2)));

__device__ inline float bf2f(u16 h) {
    u32 u = ((u32)h) << 16;
    float f;
    __builtin_memcpy(&f, &u, 4);
    return f;
}
__device__ inline u16 f2bf(float f) {
    u32 u;
    __builtin_memcpy(&u, &f, 4);
    u32 r = (u + 0x7fffu + ((u >> 16) & 1u)) >> 16;
    return (u16)r;
}
__device__ inline u32 f2u(float f) { u32 u; __builtin_memcpy(&u, &f, 4); return u; }
__device__ inline float u2f(u32 u) { float f; __builtin_memcpy(&f, &u, 4); return f; }
__device__ inline float sigm(float x) { return 1.f / (1.f + expf(-x)); }
__device__ inline float leaky(float x) { return x > 0.f ? x : 0.2f * x; }
__device__ inline float softplus(float x) {
    return x > 0.f ? x + log1pf(expf(-x)) : log1pf(expf(x));
}

// ---- coherent (device-scope) vector ops; waitcnt INSIDE asm ----
__device__ inline void cload16(const u32* p, u32* w) {
    u32x4 v0, v1, v2, v3;
    asm volatile(
        "global_load_dwordx4 %0, %4, off sc0 sc1\n\t"
        "global_load_dwordx4 %1, %4, off offset:16 sc0 sc1\n\t"
        "global_load_dwordx4 %2, %4, off offset:32 sc0 sc1\n\t"
        "global_load_dwordx4 %3, %4, off offset:48 sc0 sc1\n\t"
        "s_waitcnt vmcnt(0)"
        : "=&v"(v0), "=&v"(v1), "=&v"(v2), "=&v"(v3)
        : "v"(p)
        : "memory");
    *(u32x4*)(w) = v0;
    *(u32x4*)(w + 4) = v1;
    *(u32x4*)(w + 8) = v2;
    *(u32x4*)(w + 12) = v3;
}
__device__ inline u32 cload1(const u32* p) {
    u32 v;
    asm volatile("global_load_dword %0, %1, off sc0 sc1\n\ts_waitcnt vmcnt(0)"
                 : "=v"(v) : "v"(p) : "memory");
    return v;
}
__device__ inline u64 cload2(const u64* p) {
    u32x2 v;
    asm volatile("global_load_dwordx2 %0, %1, off sc0 sc1\n\ts_waitcnt vmcnt(0)"
                 : "=v"(v) : "v"(p) : "memory");
    return ((u64)v[1] << 32) | (u64)v[0];
}
__device__ inline void cwait() { asm volatile("s_waitcnt vmcnt(0)" ::: "memory"); }
__device__ inline void cstore1(u32* p, u32 v) {
    asm volatile("global_store_dword %0, %1, off sc0 sc1" :: "v"(p), "v"(v) : "memory");
}

// Workspace layout (bytes)
#define OFF_FLAGS  0x000000   // grp: 32 step slots @ grp*64; heavy cnt@512 gen@528
#define OFF_B1SUM  0x002000
#define OFF_WP     0x004000
#define OFF_BIAS0  0x008000
#define OFF_CPAR   0x00A000   // f32: cg1,cbeta1,cg2,cbeta2; bo1@2048, bo2@2304, cb2@2560, cb1@3072, wo2f@3584
#define OFF_H0P    0x010000   // 128x512 u32 (hi|lo<<16)
#define OFF_H1P    0x050000
#define OFF_WO1TH  0x0B0000   // 256x512 bf16
#define OFF_WO1TL  0x0F0000
#define OFF_ZF     0x130000   // pre-phase only (P1)
#define OFF_PACC   0x130000   // u64 head accumulators [grp][step 0..511][row*2+j] = 1MB.
                              //   Overlays zf/cw1f/cw2f (pre-phase only; dirty lines flushed
                              //   by P0-gbar threadfence; zeroed via coherent stores in P5).
#define OFF_CW1F   0x140000   // pre-phase only (P1)
#define OFF_CW2F   0x180000   // pre-phase only (P3)
#define OFF_CONDF  0x280000
#define OFF_YBUF   0x2C0000
#define OFF_BASE0  0x300000   // 1MB f32 (temp: wo1f in P0/P1)
#define OFF_EMBW   0x400000
#define OFF_W0HI   0x500000   // 2048x512 bf16 each
#define OFF_W0LO   0x700000
#define OFF_W1HI   0x900000
#define OFF_W1LO   0xB00000
#define OFF_WI1HI  0xD00000
#define OFF_WI1LO  0xF00000   // end 0x1100000

// Head-partial packing: X = (1<<48) + (p*2^24 + 2^40).
// count = v>>48 (==16 when all producers landed); sum = (v&mask48) - 16*2^40, scale 2^-24.
#define PSCALE 16777216.0f
#define PINV   5.9604644775390625e-8f

// heavy grid barrier (pre-phase only)
__device__ inline void gbar_heavy(int* cnt, int* gen) {
    __syncthreads();
    if (threadIdx.x == 0) {
        __threadfence();
        int g = __hip_atomic_load(gen, __ATOMIC_RELAXED, __HIP_MEMORY_SCOPE_AGENT);
        int arrived = __hip_atomic_fetch_add(cnt, 1, __ATOMIC_ACQ_REL, __HIP_MEMORY_SCOPE_AGENT);
        if (arrived == WGS - 1) {
            __hip_atomic_store(cnt, 0, __ATOMIC_RELAXED, __HIP_MEMORY_SCOPE_AGENT);
            __hip_atomic_store(gen, g + 1, __ATOMIC_RELEASE, __HIP_MEMORY_SCOPE_AGENT);
        } else {
            while (__hip_atomic_load(gen, __ATOMIC_ACQUIRE, __HIP_MEMORY_SCOPE_AGENT) == g)
                __builtin_amdgcn_s_sleep(1);
        }
        __threadfence();
    }
    __syncthreads();
}

// step-flag poll (called by wave 0; broadcast via the following __syncthreads)
__device__ inline void poll32(const u32* gf, u32 sq) {
    const int l = threadIdx.x & 31;
    for (;;) {
        u32 v = cload1(gf + l);
        if (__all((int)(v >= sq))) break;
        __builtin_amdgcn_s_sleep(4);
    }
}

// unpack 16 packed u32 (hi|lo<<16) into bf16 hi/lo planes
__device__ inline void unpack16(const u32* w, u16* ph, u16* pl) {
    u32 hd[8], ld[8];
#pragma unroll
    for (int i = 0; i < 8; ++i) {
        hd[i] = (w[2 * i] & 0xFFFFu) | (w[2 * i + 1] << 16);
        ld[i] = (w[2 * i] >> 16) | (w[2 * i + 1] & 0xFFFF0000u);
    }
    *(u32x4*)(ph) = *(const u32x4*)(hd);
    *(u32x4*)(ph + 8) = *(const u32x4*)(hd + 4);
    *(u32x4*)(pl) = *(const u32x4*)(ld);
    *(u32x4*)(pl + 8) = *(const u32x4*)(ld + 4);
}

// M=16/N=16 tile, K=512
#define MF(a, b, c) __builtin_amdgcn_mfma_f32_16x16x32_bf16(a, b, c, 0, 0, 0)

// B streamed from global, 3 chains (fp32-input fallback only)
__device__ inline f32x4 gemm16_3(const u16* __restrict__ Ah, const u16* __restrict__ Al,
                                 const u16* __restrict__ Bhb, const u16* __restrict__ Blb,
                                 int colb, int n, int q) {
    const u16* Bh = Bhb + (size_t)(colb + n) * Hn;
    const u16* Bl = Blb + (size_t)(colb + n) * Hn;
    const int a0 = n * LSTR;
    f32x4 c0 = {0.f, 0.f, 0.f, 0.f}, c1 = c0, c2 = c0;
#pragma unroll 4
    for (int it = 0; it < 16; ++it) {
        const int ko = it * 32 + q * 8;
        bf16x8 bh = *(const bf16x8*)(Bh + ko);
        bf16x8 bl = *(const bf16x8*)(Bl + ko);
        bf16x8 ah = *(const bf16x8*)(Ah + a0 + ko);
        bf16x8 al = *(const bf16x8*)(Al + a0 + ko);
        c0 = MF(ah, bh, c0);
        c1 = MF(al, bh, c1);
        c2 = MF(ah, bl, c2);
    }
    return c0 + c1 + c2;
}

// B streamed from global, 2 chains (bf16 path: weight lo-plane is exactly zero)
__device__ inline f32x4 gemm16_s2(const u16* __restrict__ Ah, const u16* __restrict__ Al,
                                  const u16* __restrict__ Bhb, int colb, int n, int q) {
    const u16* Bh = Bhb + (size_t)(colb + n) * Hn;
    const int a0 = n * LSTR;
    f32x4 c0 = {0.f, 0.f, 0.f, 0.f}, c1 = c0;
#pragma unroll 4
    for (int it = 0; it < 16; ++it) {
        const int ko = it * 32 + q * 8;
        bf16x8 bh = *(const bf16x8*)(Bh + ko);
        bf16x8 ah = *(const bf16x8*)(Ah + a0 + ko);
        bf16x8 al = *(const bf16x8*)(Al + a0 + ko);
        c0 = MF(ah, bh, c0);
        c1 = MF(al, bh, c1);
    }
    return c0 + c1;
}

// B resident in regs, 3 chains (fp32 path: wa=hi, wb=lo)
__device__ inline f32x4 gemm16_regB3(const u16* __restrict__ Ah, const u16* __restrict__ Al,
                                     const bf16x8* wa, const bf16x8* wb, int n, int q) {
    const int a0 = n * LSTR;
    f32x4 c0 = {0.f, 0.f, 0.f, 0.f}, c1 = c0, c2 = c0;
#pragma unroll
    for (int it = 0; it < 16; ++it) {
        const int ko = it * 32 + q * 8;
        bf16x8 ah = *(const bf16x8*)(Ah + a0 + ko);
        bf16x8 al = *(const bf16x8*)(Al + a0 + ko);
        c0 = MF(ah, wa[it], c0);
        c1 = MF(al, wa[it], c1);
        c2 = MF(ah, wb[it], c2);
    }
    return c0 + c1 + c2;
}

// B resident in regs, 2 chains (bf16 path)
__device__ inline f32x4 gemm16_regB2(const u16* __restrict__ Ah, const u16* __restrict__ Al,
                                     const bf16x8* wb, int n, int q) {
    const int a0 = n * LSTR;
    f32x4 c0 = {0.f, 0.f, 0.f, 0.f}, c1 = c0;
#pragma unroll
    for (int it = 0; it < 16; ++it) {
        const int ko = it * 32 + q * 8;
        bf16x8 ah = *(const bf16x8*)(Ah + a0 + ko);
        bf16x8 al = *(const bf16x8*)(Al + a0 + ko);
        c0 = MF(ah, wb[it], c0);
        c1 = MF(al, wb[it], c1);
    }
    return c0 + c1;
}

// B resident in LDS (head wo1T slice), 3 chains (fp32 fallback)
__device__ inline f32x4 gemm16_ldsB3(const u16* __restrict__ Ah, const u16* __restrict__ Al,
                                     const u16* __restrict__ Bh, const u16* __restrict__ Bl,
                                     int n, int q) {
    const int a0 = n * LSTR;
    f32x4 c0 = {0.f, 0.f, 0.f, 0.f}, c1 = c0, c2 = c0;
#pragma unroll 4
    for (int it = 0; it < 16; ++it) {
        const int ko = it * 32 + q * 8;
        bf16x8 bh = *(const bf16x8*)(Bh + a0 + ko);
        bf16x8 bl = *(const bf16x8*)(Bl + a0 + ko);
        bf16x8 ah = *(const bf16x8*)(Ah + a0 + ko);
        bf16x8 al = *(const bf16x8*)(Al + a0 + ko);
        c0 = MF(ah, bh, c0);
        c1 = MF(al, bh, c1);
        c2 = MF(ah, bl, c2);
    }
    return c0 + c1 + c2;
}

// dtype-safe staging (pre-phase)
__device__ inline void stage(float* dst, const void* src, int n, int gtid, bool isbf) {
    if (isbf) {
        const u16* s = (const u16*)src;
        for (int e = gtid; e < n; e += NALL) dst[e] = bf2f(s[e]);
    } else {
        const float* s = (const float*)src;
        for (int e = gtid; e < n; e += NALL) dst[e] = s[e];
    }
}
__device__ inline void stage_split(u16* hi, u16* lo, const void* src, int n, int gtid, bool isbf) {
    if (isbf) {
        const u16* s = (const u16*)src;
        for (int e = gtid; e < n; e += NALL) { hi[e] = s[e]; lo[e] = 0; }
    } else {
        const float* s = (const float*)src;
        for (int e = gtid; e < n; e += NALL) {
            float w = s[e];
            u16 h = f2bf(w);
            hi[e] = h;
            lo[e] = f2bf(w - bf2f(h));
        }
    }
}

template <bool ISBF>
__device__ inline float ldw(const void* p, size_t i) {
    if constexpr (ISBF) return bf2f(((const u16*)p)[i]);
    else return ((const float*)p)[i];
}

template <bool ISBF>
__device__ void phase5(const void* wih0, const void* emb, const float* __restrict__ condf,
                       const float* __restrict__ bias0f, float* __restrict__ base0,
                       float* __restrict__ embW, int gtid) {
    const int cc = gtid & 2047;
    const int bb0 = gtid >> 11;
    float b = bias0f[cc];
    float a0 = b, a1 = b, a2 = b, a3 = b;
    const float* c0p = condf + (size_t)bb0 * Hn;
    const float* c1p = condf + (size_t)(bb0 + 32) * Hn;
    const float* c2p = condf + (size_t)(bb0 + 64) * Hn;
    const float* c3p = condf + (size_t)(bb0 + 96) * Hn;
    const size_t wb = (size_t)cc * 578 + 64;
    for (int k = 0; k < Hn; ++k) {
        float w = ldw<ISBF>(wih0, wb + k);
        a0 += c0p[k] * w; a1 += c1p[k] * w; a2 += c2p[k] * w; a3 += c3p[k] * w;
    }
    base0[(size_t)bb0 * G4 + cc] = a0;
    base0[(size_t)(bb0 + 32) * G4 + cc] = a1;
    base0[(size_t)(bb0 + 64) * G4 + cc] = a2;
    base0[(size_t)(bb0 + 96) * G4 + cc] = a3;
    float e0 = 0.f, e1 = 0.f, e2 = 0.f, e3 = 0.f;
    const size_t wb2 = (size_t)cc * 578;
    for (int k = 0; k < En; ++k) {
        float w = ldw<ISBF>(wih0, wb2 + k);
        e0 += ldw<ISBF>(emb, (size_t)bb0 * En + k) * w;
        e1 += ldw<ISBF>(emb, (size_t)(bb0 + 32) * En + k) * w;
        e2 += ldw<ISBF>(emb, (size_t)(bb0 + 64) * En + k) * w;
        e3 += ldw<ISBF>(emb, (size_t)(bb0 + 96) * En + k) * w;
    }
    embW[(size_t)bb0 * G4 + cc] = e0;
    embW[(size_t)(bb0 + 32) * G4 + cc] = e1;
    embW[(size_t)(bb0 + 64) * G4 + cc] = e2;
    embW[(size_t)(bb0 + 96) * G4 + cc] = e3;
}

__device__ inline void ln_leaky_row(const float* __restrict__ x, const float* __restrict__ gamma,
                                    const float* __restrict__ beta, float* __restrict__ out,
                                    float* red) {
    int tid = threadIdx.x;
    float v = x[tid];
    float s = v, s2 = v * v;
    for (int off = 32; off; off >>= 1) {
        s += __shfl_down(s, off);
        s2 += __shfl_down(s2, off);
    }
    int wv = tid >> 6;
    if ((tid & 63) == 0) { red[wv * 2] = s; red[wv * 2 + 1] = s2; }
    __syncthreads();
    if (tid == 0) {
        float ts = 0.f, ts2 = 0.f;
        for (int i = 0; i < 8; ++i) { ts += red[i * 2]; ts2 += red[i * 2 + 1]; }
        float m = ts / 512.f;
        float var = ts2 / 512.f - m * m;
        red[16] = m;
        red[17] = rsqrtf(var + 1e-5f);
    }
    __syncthreads();
    float m = red[16], rs = red[17];
    out[tid] = leaky((v - m) * rs * gamma[tid] + beta[tid]);
    __syncthreads();
}

__global__ void init_flags_kernel(int* flags) { flags[threadIdx.x] = 0; }

__global__ __launch_bounds__(NTHR, 2) void gen_kernel(
    const int* __restrict__ char_ids, const void* z, const void* emb,
    const void* cw1, const void* cb1, const void* cg1, const void* cbeta1,
    const void* cw2, const void* cb2, const void* cg2, const void* cbeta2,
    const void* wih0, const void* whh0, const void* bih0, const void* bhh0,
    const void* wih1, const void* whh1, const void* bih1, const void* bhh1,
    const void* wo1, const void* bo1, const void* wo2, const void* bo2,
    const void* init_t, void* outp, char* __restrict__ ws) {
    __shared__ u16 lh0h[RPG * LSTR];
    __shared__ u16 lh0l[RPG * LSTR];
    __shared__ u16 lh1h[RPG * LSTR];
    __shared__ u16 lh1l[RPG * LSTR];
    __shared__ u16 lwoh[16 * LSTR];   // head wo1T slice (hi) — fp32 path only
    __shared__ u16 lwol[16 * LSTR];   // head wo1T slice (lo) — fp32 path only
    __shared__ float smemx[1024];
    __shared__ float pvs[32];
    __shared__ float red[34];

    int* flags = (int*)(ws + OFF_FLAGS);
    float* b1sum = (float*)(ws + OFF_B1SUM);
    float* wpb = (float*)(ws + OFF_WP);
    float* bias0f = (float*)(ws + OFF_BIAS0);
    float* cpar = (float*)(ws + OFF_CPAR);
    u32* h0p = (u32*)(ws + OFF_H0P);
    u32* h1p = (u32*)(ws + OFF_H1P);
    u64* paccb = (u64*)(ws + OFF_PACC);
    u16* wo1Th = (u16*)(ws + OFF_WO1TH);
    u16* wo1Tl = (u16*)(ws + OFF_WO1TL);
    float* zf = (float*)(ws + OFF_ZF);
    float* cw1f = (float*)(ws + OFF_CW1F);
    float* cw2f = (float*)(ws + OFF_CW2F);
    float* condf = (float*)(ws + OFF_CONDF);
    float* ybuf = (float*)(ws + OFF_YBUF);
    float* base0 = (float*)(ws + OFF_BASE0);
    float* embW = (float*)(ws + OFF_EMBW);
    u16* W0hi = (u16*)(ws + OFF_W0HI);
    u16* W0lo = (u16*)(ws + OFF_W0LO);
    u16* W1hi = (u16*)(ws + OFF_W1HI);
    u16* W1lo = (u16*)(ws + OFF_W1LO);
    u16* Wi1hi = (u16*)(ws + OFF_WI1HI);
    u16* Wi1lo = (u16*)(ws + OFF_WI1LO);
    float* wo1f = base0;  // temp until P5

    const bool isbf = (((const u32*)cg1)[0] == 0x3F803F80u);

    const int g = blockIdx.x;
    const int tid = threadIdx.x;
    const int wv = tid >> 6;
    const int grp = g >> 5;     // 0..7: 16 batch rows each (verified-fast mapping)
    const int ut = g & 31;      // unit block: 16 cols x 4 gates
    const int mat = wv >> 2;    // 0: whh0-side, 1: whh1/wih1-side
    const int gw = wv & 3;      // gate
    const int R0g = grp * RPG;
    const int colb = gw * 512 + ut * 16;
    const int lane = tid & 63;
    const int n = lane & 15;
    const int q = lane >> 4;
    const int gtid = g * NTHR + tid;
    const f32x4 Z4 = {0.f, 0.f, 0.f, 0.f};

    u32* gf = (u32*)flags + grp * 64;       // 32 step slots
    u32* gfl = gf + ut;
    int* hcnt = flags + 512;
    int* hgen = flags + 528;
    u64* pacc = paccb + (size_t)grp * Tn * 32;  // [step][row*2+j]

    // ---------------- P0: stage everything ----------------
    stage_split(W0hi, W0lo, whh0, G4 * Hn, gtid, isbf);
    stage_split(W1hi, W1lo, whh1, G4 * Hn, gtid, isbf);
    stage_split(Wi1hi, Wi1lo, wih1, G4 * Hn, gtid, isbf);
    stage(zf, z, Bn * Ln, gtid, isbf);
    stage(cw1f, cw1, Ln * Hn, gtid, isbf);
    stage(cw2f, cw2, Hn * Hn, gtid, isbf);
    stage(cpar + 0, cg1, 512, gtid, isbf);
    stage(cpar + 512, cbeta1, 512, gtid, isbf);
    stage(cpar + 1024, cg2, 512, gtid, isbf);
    stage(cpar + 1536, cbeta2, 512, gtid, isbf);
    stage(cpar + 2048, bo1, 256, gtid, isbf);
    stage(cpar + 2304, bo2, 2, gtid, isbf);
    stage(cpar + 2560, cb2, 512, gtid, isbf);
    stage(cpar + 3072, cb1, 512, gtid, isbf);
    stage(cpar + 3584, wo2, 256 * 2, gtid, isbf);
    stage(wo1f, wo1, Hn * 256, gtid, isbf);
    if (gtid < Bn * Hn) { cstore1(h0p + gtid, 0); cstore1(h1p + gtid, 0); }
    if (isbf) {
        if (gtid < G4) b1sum[gtid] = bf2f(((const u16*)bih1)[gtid]) + bf2f(((const u16*)bhh1)[gtid]);
        if (gtid < G4) bias0f[gtid] = bf2f(((const u16*)bih0)[gtid]) + bf2f(((const u16*)bhh0)[gtid]);
        if (gtid < 4096) {
            size_t ix = (size_t)(gtid >> 1) * 578 + 576 + (gtid & 1);
            wpb[gtid] = bf2f(((const u16*)wih0)[ix]);
        }
    } else {
        if (gtid < G4) b1sum[gtid] = ((const float*)bih1)[gtid] + ((const float*)bhh1)[gtid];
        if (gtid < G4) bias0f[gtid] = ((const float*)bih0)[gtid] + ((const float*)bhh0)[gtid];
        if (gtid < 4096) {
            size_t ix = (size_t)(gtid >> 1) * 578 + 576 + (gtid & 1);
            wpb[gtid] = ((const float*)wih0)[ix];
        }
    }
    gbar_heavy(hcnt, hgen);  // flushes dirty L2 lines of plain-staged regions (incl. PACC overlay)
    // ---------------- P1 ----------------
    if (gtid < Bn * Hn) {
        int bb = gtid >> 9, nn = gtid & 511;
        float a = cpar[3072 + nn];
        const float* zr = zf + bb * Ln;
        for (int k = 0; k < Ln; ++k) a += zr[k] * cw1f[k * Hn + nn];
        ybuf[gtid] = a;
    }
    for (int e = gtid; e < 256 * Hn; e += NALL) {
        int nn = e >> 9, kk = e & 511;
        float w = wo1f[kk * 256 + nn];
        u16 hv = f2bf(w);
        wo1Th[e] = hv;
        wo1Tl[e] = f2bf(w - bf2f(hv));
    }
    gbar_heavy(hcnt, hgen);
    if (g < Bn) ln_leaky_row(ybuf + g * Hn, cpar + 0, cpar + 512, condf + g * Hn, red);
    gbar_heavy(hcnt, hgen);
    if (g < Bn) {
        float a = cpar[2560 + tid];
        const float* crow = condf + g * Hn;
        for (int k = 0; k < Hn; ++k) a += crow[k] * cw2f[k * Hn + tid];
        ybuf[g * Hn + tid] = a;
    }
    gbar_heavy(hcnt, hgen);
    if (g < Bn) ln_leaky_row(ybuf + g * Hn, cpar + 1024, cpar + 1536, condf + g * Hn, red);
    gbar_heavy(hcnt, hgen);
    if (gtid < Bn * Hn) {
        if (isbf) phase5<true>(wih0, emb, condf, bias0f, base0, embW, gtid);
        else phase5<false>(wih0, emb, condf, bias0f, base0, embW, gtid);
    }
    // zero head accumulators (zf/cw1f/cw2f dead after P3; coherent stores)
    for (int e = gtid; e < GRPS * Tn * 32; e += NALL) {
        cstore1((u32*)paccb + 2 * e, 0);
        cstore1((u32*)paccb + 2 * e + 1, 0);
    }
    gbar_heavy(hcnt, hgen);  // L2 invalidated; pacc zeros visible before any producer add

    const bool headwg = (ut < 16);
    // ---------------- weight preload into 128 VGPRs (round-4-proven budget) ----------------
    // wA: phase-A weight hi (whh0 for mat0, whh1 for mat1)
    // wB: bf16 -> wih1-hi (mat1), wo1T head slice (head wave0), dup (others)
    //     fp32 -> lo-plane of wA's matrix
    bf16x8 wA[16], wB[16];
    {
        const u16* BhA = (mat == 0 ? W0hi : W1hi) + (size_t)(colb + n) * Hn;
        const u16* BhB;
        if (isbf) {
            if (mat == 1) BhB = Wi1hi + (size_t)(colb + n) * Hn;
            else if (headwg && wv == 0) BhB = wo1Th + (size_t)(ut * 16 + n) * Hn;
            else BhB = BhA;
        } else {
            BhB = (mat == 0 ? W0lo : W1lo) + (size_t)(colb + n) * Hn;
        }
#pragma unroll
        for (int it = 0; it < 16; ++it) {
            wA[it] = *(const bf16x8*)(BhA + it * 32 + q * 8);
            wB[it] = *(const bf16x8*)(BhB + it * 32 + q * 8);
        }
    }
    // head wo1T slice -> LDS (fp32 fallback only; bf16 path has it in wave0's wB regs)
    if (!isbf && headwg) {
        for (int e = tid; e < 16 * Hn; e += NTHR) {
            int col = e >> 9, k = e & 511;
            lwoh[col * LSTR + k] = wo1Th[(size_t)(ut * 16 + col) * Hn + k];
            lwol[col * LSTR + k] = wo1Tl[(size_t)(ut * 16 + col) * Hn + k];
        }
    }

    // ---------------- main loop ----------------
    float c0 = 0.f, c1 = 0.f;
    const int lr = tid >> 4;          // local row 0..15 (for tid<256)
    const int un = tid & 15;
    const int bb = R0g + lr;
    const int uu = ut * 16 + un;
    const float* bo1f = cpar + 2048;
    const float* bo2f = cpar + 2304;
    const float* wo2f = cpar + 3584;
    const int srow = tid >> 5;        // staging row 0..15
    const int blk = tid & 31;         // staging col-block == producer ut
    const int kub = blk * 16;         // staging u32 offset
    f32x4 acc1c = Z4;

    for (int e = tid; e < RPG * LSTR; e += NTHR) {
        lh0h[e] = 0; lh0l[e] = 0; lh1h[e] = 0; lh1l[e] = 0;
    }
    if (tid < 32) pvs[tid] = isbf ? bf2f(((const u16*)init_t)[tid & 1])
                                  : ((const float*)init_t)[tid & 1];

    for (int t = 0; t < Tn; ++t) {
        // ==== A: stage h1(t-1); head (ut<16 wave0) -> atomic acc; main GEMMs; gates0 ====
        if (t >= 1) {
            if (wv == 0) poll32(gf, 2 * (u32)t);
            __syncthreads();
            if (blk != ut) {  // own block was written to LDS directly by gates1
                u32 w[16];
                cload16(h1p + (size_t)(R0g + srow) * Hn + kub, w);
                unpack16(w, lh1h + srow * LSTR + kub, lh1l + srow * LSTR + kub);
            }
        }
        __syncthreads();
        if (headwg && wv == 0 && t >= 1) {
            f32x4 ha = isbf ? gemm16_regB2(lh1h, lh1l, wB, n, q)
                            : gemm16_ldsB3(lh1h, lh1l, lwoh, lwol, n, q);
            float p[4][2];
#pragma unroll
            for (int r = 0; r < 4; ++r) {
                float hv = leaky(ha[r] + bo1f[ut * 16 + n]);
                p[r][0] = hv * wo2f[(ut * 16 + n) * 2];
                p[r][1] = hv * wo2f[(ut * 16 + n) * 2 + 1];
            }
#pragma unroll
            for (int r = 0; r < 4; ++r)
#pragma unroll
                for (int j = 0; j < 2; ++j) {
                    float s = p[r][j];
                    s += __shfl_xor(s, 1, 16);
                    s += __shfl_xor(s, 2, 16);
                    s += __shfl_xor(s, 4, 16);
                    s += __shfl_xor(s, 8, 16);
                    p[r][j] = s;
                }
            if (n == 0) {
                u64* acc = pacc + (size_t)(t - 1) * 32;
#pragma unroll
                for (int r = 0; r < 4; ++r)
#pragma unroll
                    for (int j = 0; j < 2; ++j) {
                        int row = q * 4 + r;
                        long long fx = (long long)llrintf(p[r][j] * PSCALE);
                        u64 x = (1ULL << 48) + (u64)(fx + (1LL << 40));
                        atomicAdd(acc + (row * 2 + j), x);  // fire-and-forget: no drain, no flag
                    }
            }
        }
        if (mat == 0) {
            f32x4 a = isbf ? gemm16_regB2(lh0h, lh0l, wA, n, q)
                           : gemm16_regB3(lh0h, lh0l, wA, wB, n, q);
#pragma unroll
            for (int r = 0; r < 4; ++r)
                smemx[gw * 256 + (q * 4 + r) * 16 + n] = a[r];
        } else {
            acc1c = isbf ? gemm16_regB2(lh1h, lh1l, wA, n, q)
                         : gemm16_regB3(lh1h, lh1l, wA, wB, n, q);
        }
        if (t >= 1 && wv == 0 && tid < 32) {
            // consume: poll one u64 until all 16 producers landed; re-read = post-commit
            int row = tid >> 1, j = tid & 1;
            u64* slot = pacc + (size_t)(t - 1) * 32 + tid;
            u64 v;
            for (;;) {
                v = cload2(slot);
                if ((v >> 48) == 16) break;
                __builtin_amdgcn_s_sleep(2);
            }
            v = cload2(slot);
            long long fx = (long long)(v & 0xFFFFFFFFFFFFULL) - (16LL << 40);
            float s = bo2f[j] + (float)fx * PINV;
            float y = softplus(s) + 0.005f;
            pvs[row * 2 + j] = y;
            if (ut == 0) {
                size_t oi = ((size_t)(R0g + row) * Tn + (t - 1)) * 2 + j;
                if (isbf) ((u16*)outp)[oi] = f2bf(y);
                else ((float*)outp)[oi] = y;
            }
        }
        __syncthreads();
        if (tid < 256) {
            int id = char_ids[bb * Tn + t];
            float pv0 = pvs[lr * 2], pv1 = pvs[lr * 2 + 1];
            float gv[4];
#pragma unroll
            for (int gi = 0; gi < 4; ++gi) {
                int cc = gi * 512 + uu;
                gv[gi] = smemx[gi * 256 + lr * 16 + un] + base0[(size_t)bb * G4 + cc] +
                         embW[(size_t)id * G4 + cc] + pv0 * wpb[2 * cc] + pv1 * wpb[2 * cc + 1];
            }
            float ig = sigm(gv[0]), fg = sigm(gv[1]), gg = tanhf(gv[2]), og = sigm(gv[3]);
            c0 = fg * c0 + ig * gg;
            float h = og * tanhf(c0);
            u16 hv = f2bf(h);
            u16 lv = f2bf(h - bf2f(hv));
            lh0h[lr * LSTR + uu] = hv;  // own block direct to LDS
            lh0l[lr * LSTR + uu] = lv;
            cstore1(h0p + (size_t)bb * Hn + uu, (u32)hv | ((u32)lv << 16));
        }
        cwait();
        __syncthreads();
        if (tid == 0) cstore1(gfl, 2 * (u32)t + 1);

        // ==== B: stage h0(t); wih1 GEMM (mat1 waves); gates1 -> h1(t) ====
        if (wv == 0) poll32(gf, 2 * (u32)t + 1);
        __syncthreads();
        if (blk != ut) {
            u32 w[16];
            cload16(h0p + (size_t)(R0g + srow) * Hn + kub, w);
            unpack16(w, lh0h + srow * LSTR + kub, lh0l + srow * LSTR + kub);
        }
        __syncthreads();
        if (mat == 1) {
            f32x4 a = isbf ? gemm16_s2(lh0h, lh0l, Wi1hi, colb, n, q)
                           : gemm16_3(lh0h, lh0l, Wi1hi, Wi1lo, colb, n, q);
            acc1c = acc1c + a;
#pragma unroll
            for (int r = 0; r < 4; ++r)
                smemx[gw * 256 + (q * 4 + r) * 16 + n] = acc1c[r];
        }
        __syncthreads();
        if (tid < 256) {
            float gv[4];
#pragma unroll
            for (int gi = 0; gi < 4; ++gi) {
                int cc = gi * 512 + uu;
                gv[gi] = smemx[gi * 256 + lr * 16 + un] + b1sum[cc];
            }
            float ig = sigm(gv[0]), fg = sigm(gv[1]), gg = tanhf(gv[2]), og = sigm(gv[3]);
            c1 = fg * c1 + ig * gg;
            float h = og * tanhf(c1);
            u16 hv = f2bf(h);
            u16 lv = f2bf(h - bf2f(hv));
            lh1h[lr * LSTR + uu] = hv;  // own block direct to LDS
            lh1l[lr * LSTR + uu] = lv;
            cstore1(h1p + (size_t)bb * Hn + uu, (u32)hv | ((u32)lv << 16));
        }
        cwait();
        __syncthreads();
        if (tid == 0) cstore1(gfl, 2 * (u32)t + 2);
    }

    // ---------------- epilogue: head for t = 511 (acc slot Tn-1) ----------------
    if (wv == 0) poll32(gf, 2 * (u32)Tn);
    __syncthreads();
    if (blk != ut) {
        u32 w[16];
        cload16(h1p + (size_t)(R0g + srow) * Hn + kub, w);
        unpack16(w, lh1h + srow * LSTR + kub, lh1l + srow * LSTR + kub);
    }
    __syncthreads();
    if (headwg && wv == 0) {
        f32x4 ha = isbf ? gemm16_regB2(lh1h, lh1l, wB, n, q)
                        : gemm16_ldsB3(lh1h, lh1l, lwoh, lwol, n, q);
        float p[4][2];
#pragma unroll
        for (int r = 0; r < 4; ++r) {
            float hv = leaky(ha[r] + bo1f[ut * 16 + n]);
            p[r][0] = hv * wo2f[(ut * 16 + n) * 2];
            p[r][1] = hv * wo2f[(ut * 16 + n) * 2 + 1];
        }
#pragma unroll
        for (int r = 0; r < 4; ++r)
#pragma unroll
            for (int j = 0; j < 2; ++j) {
                float s = p[r][j];
                s += __shfl_xor(s, 1, 16);
                s += __shfl_xor(s, 2, 16);
                s += __shfl_xor(s, 4, 16);
                s += __shfl_xor(s, 8, 16);
                p[r][j] = s;
            }
        if (n == 0) {
            u64* acc = pacc + (size_t)(Tn - 1) * 32;
#pragma unroll
            for (int r = 0; r < 4; ++r)
#pragma unroll
                for (int j = 0; j < 2; ++j) {
                    int row = q * 4 + r;
                    long long fx = (long long)llrintf(p[r][j] * PSCALE);
                    u64 x = (1ULL << 48) + (u64)(fx + (1LL << 40));
                    atomicAdd(acc + (row * 2 + j), x);
                }
        }
    }
    if (ut == 0 && wv == 0 && tid < 32) {
        int row = tid >> 1, j = tid & 1;
        u64* slot = pacc + (size_t)(Tn - 1) * 32 + tid;
        u64 v;
        for (;;) {
            v = cload2(slot);
            if ((v >> 48) == 16) break;
            __builtin_amdgcn_s_sleep(2);
        }
        v = cload2(slot);
        long long fx = (long long)(v & 0xFFFFFFFFFFFFULL) - (16LL << 40);
        float s = bo2f[j] + (float)fx * PINV;
        float y = softplus(s) + 0.005f;
        size_t oi = ((size_t)(R0g + row) * Tn + (Tn - 1)) * 2 + j;
        if (isbf) ((u16*)outp)[oi] = f2bf(y);
        else ((float*)outp)[oi] = y;
    }
}

extern "C" void kernel_launch(void* const* d_in, const int* in_sizes, int n_in,
                              void* d_out, int out_size, void* d_ws, size_t ws_size,
                              hipStream_t stream) {
    (void)in_sizes; (void)n_in; (void)out_size; (void)ws_size;
    init_flags_kernel<<<1, 1024, 0, stream>>>((int*)d_ws);
    gen_kernel<<<WGS, NTHR, 0, stream>>>(
        (const int*)d_in[0], d_in[1], d_in[2], d_in[3], d_in[4], d_in[5], d_in[6], d_in[7],
        d_in[8], d_in[9], d_in[10], d_in[11], d_in[12], d_in[13], d_in[14], d_in[15], d_in[16],
        d_in[17], d_in[18], d_in[19], d_in[20], d_in[21], d_in[22], d_in[23],
        d_out, (char*)d_ws);
}

// Round 8
// 8602.829 us; speedup vs baseline: 1.5994x; 1.5994x over previous
//
#include <hip/hip_runtime.h>

// Problem constants
#define Bn 128
#define Tn 512
#define Vn 128
#define En 64
#define Ln 128
#define Hn 512
#define G4 2048
#define WGS 256
#define NTHR 512
#define NALL (WGS * NTHR)
#define LSTR 520   // LDS row stride in u16 (16B-aligned rows)
#define GRPS 8
#define WPG 32     // WGs per group
#define RPG 16     // batch rows per group

typedef unsigned short u16;
typedef unsigned int u32;
typedef __bf16 bf16x8 __attribute__((ext_vector_type(8)));
typedef float f32x4 __attribute__((ext_vector_type(4)));
typedef u32 u32x4 __attribute__((ext_vector_type(4)));

__device__ inline float bf2f(u16 h) {
    u32 u = ((u32)h) << 16;
    float f;
    __builtin_memcpy(&f, &u, 4);
    return f;
}
__device__ inline u16 f2bf(float f) {
    u32 u;
    __builtin_memcpy(&u, &f, 4);
    u32 r = (u + 0x7fffu + ((u >> 16) & 1u)) >> 16;
    return (u16)r;
}
__device__ inline u32 f2u(float f) { u32 u; __builtin_memcpy(&u, &f, 4); return u; }
__device__ inline float u2f(u32 u) { float f; __builtin_memcpy(&f, &u, 4); return f; }
__device__ inline float sigm(float x) { return 1.f / (1.f + expf(-x)); }
__device__ inline float leaky(float x) { return x > 0.f ? x : 0.2f * x; }
__device__ inline float softplus(float x) {
    return x > 0.f ? x + log1pf(expf(-x)) : log1pf(expf(x));
}

// ---- coherent (device-scope) vector ops; waitcnt INSIDE asm ----
__device__ inline void cload16(const u32* p, u32* w) {
    u32x4 v0, v1, v2, v3;
    asm volatile(
        "global_load_dwordx4 %0, %4, off sc0 sc1\n\t"
        "global_load_dwordx4 %1, %4, off offset:16 sc0 sc1\n\t"
        "global_load_dwordx4 %2, %4, off offset:32 sc0 sc1\n\t"
        "global_load_dwordx4 %3, %4, off offset:48 sc0 sc1\n\t"
        "s_waitcnt vmcnt(0)"
        : "=&v"(v0), "=&v"(v1), "=&v"(v2), "=&v"(v3)
        : "v"(p)
        : "memory");
    *(u32x4*)(w) = v0;
    *(u32x4*)(w + 4) = v1;
    *(u32x4*)(w + 8) = v2;
    *(u32x4*)(w + 12) = v3;
}
__device__ inline u32 cload1(const u32* p) {
    u32 v;
    asm volatile("global_load_dword %0, %1, off sc0 sc1\n\ts_waitcnt vmcnt(0)"
                 : "=v"(v) : "v"(p) : "memory");
    return v;
}
__device__ inline void cwait() { asm volatile("s_waitcnt vmcnt(0)" ::: "memory"); }
__device__ inline void cstore1(u32* p, u32 v) {
    asm volatile("global_store_dword %0, %1, off sc0 sc1" :: "v"(p), "v"(v) : "memory");
}

// Workspace layout (bytes)
#define OFF_FLAGS  0x000000   // grp: 32 step slots @ grp*64, 16 head slots @ grp*64+32; heavy cnt@512 gen@528
#define OFF_B1SUM  0x002000
#define OFF_WP     0x004000
#define OFF_BIAS0  0x008000
#define OFF_CPAR   0x00A000   // f32: cg1,cbeta1,cg2,cbeta2; bo1@2048, bo2@2304, cb2@2560, cb1@3072, wo2f@3584
#define OFF_H0P    0x010000   // 128x512 u32 (hi|lo<<16)
#define OFF_H1P    0x050000
#define OFF_PART   0x090000   // partials: grp*1024 f32: [row][j][16]
#define OFF_WO1TH  0x0B0000   // 256x512 bf16
#define OFF_WO1TL  0x0F0000
#define OFF_ZF     0x130000
#define OFF_CW1F   0x140000
#define OFF_CW2F   0x180000
#define OFF_CONDF  0x280000
#define OFF_YBUF   0x2C0000
#define OFF_BASE0  0x300000   // 1MB f32 (temp: wo1f in P0/P1)
#define OFF_EMBW   0x400000
#define OFF_W0HI   0x500000   // 2048x512 bf16 each
#define OFF_W0LO   0x700000
#define OFF_W1HI   0x900000
#define OFF_W1LO   0xB00000
#define OFF_WI1HI  0xD00000
#define OFF_WI1LO  0xF00000   // end 0x1100000

// heavy grid barrier (pre-phase only)
__device__ inline void gbar_heavy(int* cnt, int* gen) {
    __syncthreads();
    if (threadIdx.x == 0) {
        __threadfence();
        int g = __hip_atomic_load(gen, __ATOMIC_RELAXED, __HIP_MEMORY_SCOPE_AGENT);
        int arrived = __hip_atomic_fetch_add(cnt, 1, __ATOMIC_ACQ_REL, __HIP_MEMORY_SCOPE_AGENT);
        if (arrived == WGS - 1) {
            __hip_atomic_store(cnt, 0, __ATOMIC_RELAXED, __HIP_MEMORY_SCOPE_AGENT);
            __hip_atomic_store(gen, g + 1, __ATOMIC_RELEASE, __HIP_MEMORY_SCOPE_AGENT);
        } else {
            while (__hip_atomic_load(gen, __ATOMIC_ACQUIRE, __HIP_MEMORY_SCOPE_AGENT) == g)
                __builtin_amdgcn_s_sleep(1);
        }
        __threadfence();
    }
    __syncthreads();
}

// polls (broadcast decision via __all within the polling wave)
__device__ inline void poll32(const u32* gf, u32 sq) {
    const int l = threadIdx.x & 31;
    for (;;) {
        u32 v = cload1(gf + l);
        if (__all((int)(v >= sq))) break;
        __builtin_amdgcn_s_sleep(2);
    }
}
__device__ inline void poll16(const u32* gf, u32 sq) {
    const int l = threadIdx.x & 15;
    for (;;) {
        u32 v = cload1(gf + l);
        if (__all((int)(v >= sq))) break;
        __builtin_amdgcn_s_sleep(2);
    }
}

// unpack 16 packed u32 (hi|lo<<16) into bf16 hi/lo planes
__device__ inline void unpack16(const u32* w, u16* ph, u16* pl) {
    u32 hd[8], ld[8];
#pragma unroll
    for (int i = 0; i < 8; ++i) {
        hd[i] = (w[2 * i] & 0xFFFFu) | (w[2 * i + 1] << 16);
        ld[i] = (w[2 * i] >> 16) | (w[2 * i + 1] & 0xFFFF0000u);
    }
    *(u32x4*)(ph) = *(const u32x4*)(hd);
    *(u32x4*)(ph + 8) = *(const u32x4*)(hd + 4);
    *(u32x4*)(pl) = *(const u32x4*)(ld);
    *(u32x4*)(pl + 8) = *(const u32x4*)(ld + 4);
}

// M=16/N=16 tile, K=512
#define MF(a, b, c) __builtin_amdgcn_mfma_f32_16x16x32_bf16(a, b, c, 0, 0, 0)

// B streamed from global, 3 chains (fp32-input fallback only)
__device__ inline f32x4 gemm16_3(const u16* __restrict__ Ah, const u16* __restrict__ Al,
                                 const u16* __restrict__ Bhb, const u16* __restrict__ Blb,
                                 int colb, int n, int q) {
    const u16* Bh = Bhb + (size_t)(colb + n) * Hn;
    const u16* Bl = Blb + (size_t)(colb + n) * Hn;
    const int a0 = n * LSTR;
    f32x4 c0 = {0.f, 0.f, 0.f, 0.f}, c1 = c0, c2 = c0;
#pragma unroll 4
    for (int it = 0; it < 16; ++it) {
        const int ko = it * 32 + q * 8;
        bf16x8 bh = *(const bf16x8*)(Bh + ko);
        bf16x8 bl = *(const bf16x8*)(Bl + ko);
        bf16x8 ah = *(const bf16x8*)(Ah + a0 + ko);
        bf16x8 al = *(const bf16x8*)(Al + a0 + ko);
        c0 = MF(ah, bh, c0);
        c1 = MF(al, bh, c1);
        c2 = MF(ah, bl, c2);
    }
    return c0 + c1 + c2;
}

// B streamed from global, 2 chains (bf16 path: weight lo-plane is exactly zero)
__device__ inline f32x4 gemm16_s2(const u16* __restrict__ Ah, const u16* __restrict__ Al,
                                  const u16* __restrict__ Bhb, int colb, int n, int q) {
    const u16* Bh = Bhb + (size_t)(colb + n) * Hn;
    const int a0 = n * LSTR;
    f32x4 c0 = {0.f, 0.f, 0.f, 0.f}, c1 = c0;
#pragma unroll 4
    for (int it = 0; it < 16; ++it) {
        const int ko = it * 32 + q * 8;
        bf16x8 bh = *(const bf16x8*)(Bh + ko);
        bf16x8 ah = *(const bf16x8*)(Ah + a0 + ko);
        bf16x8 al = *(const bf16x8*)(Al + a0 + ko);
        c0 = MF(ah, bh, c0);
        c1 = MF(al, bh, c1);
    }
    return c0 + c1;
}

// B resident in regs, 3 chains (fp32 path: wa=hi, wb=lo)
__device__ inline f32x4 gemm16_regB3(const u16* __restrict__ Ah, const u16* __restrict__ Al,
                                     const bf16x8* wa, const bf16x8* wb, int n, int q) {
    const int a0 = n * LSTR;
    f32x4 c0 = {0.f, 0.f, 0.f, 0.f}, c1 = c0, c2 = c0;
#pragma unroll
    for (int it = 0; it < 16; ++it) {
        const int ko = it * 32 + q * 8;
        bf16x8 ah = *(const bf16x8*)(Ah + a0 + ko);
        bf16x8 al = *(const bf16x8*)(Al + a0 + ko);
        c0 = MF(ah, wa[it], c0);
        c1 = MF(al, wa[it], c1);
        c2 = MF(ah, wb[it], c2);
    }
    return c0 + c1 + c2;
}

// B resident in regs, 2 chains (bf16 path)
__device__ inline f32x4 gemm16_regB2(const u16* __restrict__ Ah, const u16* __restrict__ Al,
                                     const bf16x8* wb, int n, int q) {
    const int a0 = n * LSTR;
    f32x4 c0 = {0.f, 0.f, 0.f, 0.f}, c1 = c0;
#pragma unroll
    for (int it = 0; it < 16; ++it) {
        const int ko = it * 32 + q * 8;
        bf16x8 ah = *(const bf16x8*)(Ah + a0 + ko);
        bf16x8 al = *(const bf16x8*)(Al + a0 + ko);
        c0 = MF(ah, wb[it], c0);
        c1 = MF(al, wb[it], c1);
    }
    return c0 + c1;
}

// B resident in LDS (head wo1T slice), 3 chains (fp32 fallback)
__device__ inline f32x4 gemm16_ldsB3(const u16* __restrict__ Ah, const u16* __restrict__ Al,
                                     const u16* __restrict__ Bh, const u16* __restrict__ Bl,
                                     int n, int q) {
    const int a0 = n * LSTR;
    f32x4 c0 = {0.f, 0.f, 0.f, 0.f}, c1 = c0, c2 = c0;
#pragma unroll 4
    for (int it = 0; it < 16; ++it) {
        const int ko = it * 32 + q * 8;
        bf16x8 bh = *(const bf16x8*)(Bh + a0 + ko);
        bf16x8 bl = *(const bf16x8*)(Bl + a0 + ko);
        bf16x8 ah = *(const bf16x8*)(Ah + a0 + ko);
        bf16x8 al = *(const bf16x8*)(Al + a0 + ko);
        c0 = MF(ah, bh, c0);
        c1 = MF(al, bh, c1);
        c2 = MF(ah, bl, c2);
    }
    return c0 + c1 + c2;
}

// dtype-safe staging (pre-phase)
__device__ inline void stage(float* dst, const void* src, int n, int gtid, bool isbf) {
    if (isbf) {
        const u16* s = (const u16*)src;
        for (int e = gtid; e < n; e += NALL) dst[e] = bf2f(s[e]);
    } else {
        const float* s = (const float*)src;
        for (int e = gtid; e < n; e += NALL) dst[e] = s[e];
    }
}
__device__ inline void stage_split(u16* hi, u16* lo, const void* src, int n, int gtid, bool isbf) {
    if (isbf) {
        const u16* s = (const u16*)src;
        for (int e = gtid; e < n; e += NALL) { hi[e] = s[e]; lo[e] = 0; }
    } else {
        const float* s = (const float*)src;
        for (int e = gtid; e < n; e += NALL) {
            float w = s[e];
            u16 h = f2bf(w);
            hi[e] = h;
            lo[e] = f2bf(w - bf2f(h));
        }
    }
}

template <bool ISBF>
__device__ inline float ldw(const void* p, size_t i) {
    if constexpr (ISBF) return bf2f(((const u16*)p)[i]);
    else return ((const float*)p)[i];
}

template <bool ISBF>
__device__ void phase5(const void* wih0, const void* emb, const float* __restrict__ condf,
                       const float* __restrict__ bias0f, float* __restrict__ base0,
                       float* __restrict__ embW, int gtid) {
    const int cc = gtid & 2047;
    const int bb0 = gtid >> 11;
    float b = bias0f[cc];
    float a0 = b, a1 = b, a2 = b, a3 = b;
    const float* c0p = condf + (size_t)bb0 * Hn;
    const float* c1p = condf + (size_t)(bb0 + 32) * Hn;
    const float* c2p = condf + (size_t)(bb0 + 64) * Hn;
    const float* c3p = condf + (size_t)(bb0 + 96) * Hn;
    const size_t wb = (size_t)cc * 578 + 64;
    for (int k = 0; k < Hn; ++k) {
        float w = ldw<ISBF>(wih0, wb + k);
        a0 += c0p[k] * w; a1 += c1p[k] * w; a2 += c2p[k] * w; a3 += c3p[k] * w;
    }
    base0[(size_t)bb0 * G4 + cc] = a0;
    base0[(size_t)(bb0 + 32) * G4 + cc] = a1;
    base0[(size_t)(bb0 + 64) * G4 + cc] = a2;
    base0[(size_t)(bb0 + 96) * G4 + cc] = a3;
    float e0 = 0.f, e1 = 0.f, e2 = 0.f, e3 = 0.f;
    const size_t wb2 = (size_t)cc * 578;
    for (int k = 0; k < En; ++k) {
        float w = ldw<ISBF>(wih0, wb2 + k);
        e0 += ldw<ISBF>(emb, (size_t)bb0 * En + k) * w;
        e1 += ldw<ISBF>(emb, (size_t)(bb0 + 32) * En + k) * w;
        e2 += ldw<ISBF>(emb, (size_t)(bb0 + 64) * En + k) * w;
        e3 += ldw<ISBF>(emb, (size_t)(bb0 + 96) * En + k) * w;
    }
    embW[(size_t)bb0 * G4 + cc] = e0;
    embW[(size_t)(bb0 + 32) * G4 + cc] = e1;
    embW[(size_t)(bb0 + 64) * G4 + cc] = e2;
    embW[(size_t)(bb0 + 96) * G4 + cc] = e3;
}

__device__ inline void ln_leaky_row(const float* __restrict__ x, const float* __restrict__ gamma,
                                    const float* __restrict__ beta, float* __restrict__ out,
                                    float* red) {
    int tid = threadIdx.x;
    float v = x[tid];
    float s = v, s2 = v * v;
    for (int off = 32; off; off >>= 1) {
        s += __shfl_down(s, off);
        s2 += __shfl_down(s2, off);
    }
    int wv = tid >> 6;
    if ((tid & 63) == 0) { red[wv * 2] = s; red[wv * 2 + 1] = s2; }
    __syncthreads();
    if (tid == 0) {
        float ts = 0.f, ts2 = 0.f;
        for (int i = 0; i < 8; ++i) { ts += red[i * 2]; ts2 += red[i * 2 + 1]; }
        float m = ts / 512.f;
        float var = ts2 / 512.f - m * m;
        red[16] = m;
        red[17] = rsqrtf(var + 1e-5f);
    }
    __syncthreads();
    float m = red[16], rs = red[17];
    out[tid] = leaky((v - m) * rs * gamma[tid] + beta[tid]);
    __syncthreads();
}

__global__ void init_flags_kernel(int* flags) { flags[threadIdx.x] = 0; }

__global__ __launch_bounds__(NTHR, 2) void gen_kernel(
    const int* __restrict__ char_ids, const void* z, const void* emb,
    const void* cw1, const void* cb1, const void* cg1, const void* cbeta1,
    const void* cw2, const void* cb2, const void* cg2, const void* cbeta2,
    const void* wih0, const void* whh0, const void* bih0, const void* bhh0,
    const void* wih1, const void* whh1, const void* bih1, const void* bhh1,
    const void* wo1, const void* bo1, const void* wo2, const void* bo2,
    const void* init_t, void* outp, char* __restrict__ ws) {
    __shared__ u16 lh0h[RPG * LSTR];
    __shared__ u16 lh0l[RPG * LSTR];
    __shared__ u16 lh1h[RPG * LSTR];
    __shared__ u16 lh1l[RPG * LSTR];
    __shared__ u16 lwoh[16 * LSTR];   // head wo1T slice (hi) — fp32 path only
    __shared__ u16 lwol[16 * LSTR];   // head wo1T slice (lo) — fp32 path only
    __shared__ float smemx[1024];
    __shared__ float pvs[32];
    __shared__ float red[34];

    int* flags = (int*)(ws + OFF_FLAGS);
    float* b1sum = (float*)(ws + OFF_B1SUM);
    float* wpb = (float*)(ws + OFF_WP);
    float* bias0f = (float*)(ws + OFF_BIAS0);
    float* cpar = (float*)(ws + OFF_CPAR);
    u32* h0p = (u32*)(ws + OFF_H0P);
    u32* h1p = (u32*)(ws + OFF_H1P);
    float* partf = (float*)(ws + OFF_PART);
    u16* wo1Th = (u16*)(ws + OFF_WO1TH);
    u16* wo1Tl = (u16*)(ws + OFF_WO1TL);
    float* zf = (float*)(ws + OFF_ZF);
    float* cw1f = (float*)(ws + OFF_CW1F);
    float* cw2f = (float*)(ws + OFF_CW2F);
    float* condf = (float*)(ws + OFF_CONDF);
    float* ybuf = (float*)(ws + OFF_YBUF);
    float* base0 = (float*)(ws + OFF_BASE0);
    float* embW = (float*)(ws + OFF_EMBW);
    u16* W0hi = (u16*)(ws + OFF_W0HI);
    u16* W0lo = (u16*)(ws + OFF_W0LO);
    u16* W1hi = (u16*)(ws + OFF_W1HI);
    u16* W1lo = (u16*)(ws + OFF_W1LO);
    u16* Wi1hi = (u16*)(ws + OFF_WI1HI);
    u16* Wi1lo = (u16*)(ws + OFF_WI1LO);
    float* wo1f = base0;  // temp until P5

    const bool isbf = (((const u32*)cg1)[0] == 0x3F803F80u);

    const int g = blockIdx.x;
    const int tid = threadIdx.x;
    const int wv = tid >> 6;
    const int grp = g >> 5;     // 0..7: 16 batch rows each (verified-fast mapping)
    const int ut = g & 31;      // unit block: 16 cols x 4 gates
    const int mat = wv >> 2;    // 0: whh0-side, 1: whh1/wih1-side
    const int gw = wv & 3;      // gate
    const int R0g = grp * RPG;
    const int colb = gw * 512 + ut * 16;
    const int lane = tid & 63;
    const int n = lane & 15;
    const int q = lane >> 4;
    const int gtid = g * NTHR + tid;
    const f32x4 Z4 = {0.f, 0.f, 0.f, 0.f};

    u32* gf = (u32*)flags + grp * 64;       // 32 step slots
    u32* gf2 = (u32*)flags + grp * 64 + 32; // 16 head slots
    u32* gfl = gf + ut;
    int* hcnt = flags + 512;
    int* hgen = flags + 528;
    float* part = partf + grp * 1024;       // [row][j][16]

    // ---------------- P0: stage everything ----------------
    stage_split(W0hi, W0lo, whh0, G4 * Hn, gtid, isbf);
    stage_split(W1hi, W1lo, whh1, G4 * Hn, gtid, isbf);
    stage_split(Wi1hi, Wi1lo, wih1, G4 * Hn, gtid, isbf);
    stage(zf, z, Bn * Ln, gtid, isbf);
    stage(cw1f, cw1, Ln * Hn, gtid, isbf);
    stage(cw2f, cw2, Hn * Hn, gtid, isbf);
    stage(cpar + 0, cg1, 512, gtid, isbf);
    stage(cpar + 512, cbeta1, 512, gtid, isbf);
    stage(cpar + 1024, cg2, 512, gtid, isbf);
    stage(cpar + 1536, cbeta2, 512, gtid, isbf);
    stage(cpar + 2048, bo1, 256, gtid, isbf);
    stage(cpar + 2304, bo2, 2, gtid, isbf);
    stage(cpar + 2560, cb2, 512, gtid, isbf);
    stage(cpar + 3072, cb1, 512, gtid, isbf);
    stage(cpar + 3584, wo2, 256 * 2, gtid, isbf);
    stage(wo1f, wo1, Hn * 256, gtid, isbf);
    if (gtid < Bn * Hn) { cstore1(h0p + gtid, 0); cstore1(h1p + gtid, 0); }
    if (isbf) {
        if (gtid < G4) b1sum[gtid] = bf2f(((const u16*)bih1)[gtid]) + bf2f(((const u16*)bhh1)[gtid]);
        if (gtid < G4) bias0f[gtid] = bf2f(((const u16*)bih0)[gtid]) + bf2f(((const u16*)bhh0)[gtid]);
        if (gtid < 4096) {
            size_t ix = (size_t)(gtid >> 1) * 578 + 576 + (gtid & 1);
            wpb[gtid] = bf2f(((const u16*)wih0)[ix]);
        }
    } else {
        if (gtid < G4) b1sum[gtid] = ((const float*)bih1)[gtid] + ((const float*)bhh1)[gtid];
        if (gtid < G4) bias0f[gtid] = ((const float*)bih0)[gtid] + ((const float*)bhh0)[gtid];
        if (gtid < 4096) {
            size_t ix = (size_t)(gtid >> 1) * 578 + 576 + (gtid & 1);
            wpb[gtid] = ((const float*)wih0)[ix];
        }
    }
    gbar_heavy(hcnt, hgen);
    // ---------------- P1 ----------------
    if (gtid < Bn * Hn) {
        int bb = gtid >> 9, nn = gtid & 511;
        float a = cpar[3072 + nn];
        const float* zr = zf + bb * Ln;
        for (int k = 0; k < Ln; ++k) a += zr[k] * cw1f[k * Hn + nn];
        ybuf[gtid] = a;
    }
    for (int e = gtid; e < 256 * Hn; e += NALL) {
        int nn = e >> 9, kk = e & 511;
        float w = wo1f[kk * 256 + nn];
        u16 hv = f2bf(w);
        wo1Th[e] = hv;
        wo1Tl[e] = f2bf(w - bf2f(hv));
    }
    gbar_heavy(hcnt, hgen);
    if (g < Bn) ln_leaky_row(ybuf + g * Hn, cpar + 0, cpar + 512, condf + g * Hn, red);
    gbar_heavy(hcnt, hgen);
    if (g < Bn) {
        float a = cpar[2560 + tid];
        const float* crow = condf + g * Hn;
        for (int k = 0; k < Hn; ++k) a += crow[k] * cw2f[k * Hn + tid];
        ybuf[g * Hn + tid] = a;
    }
    gbar_heavy(hcnt, hgen);
    if (g < Bn) ln_leaky_row(ybuf + g * Hn, cpar + 1024, cpar + 1536, condf + g * Hn, red);
    gbar_heavy(hcnt, hgen);
    if (gtid < Bn * Hn) {
        if (isbf) phase5<true>(wih0, emb, condf, bias0f, base0, embW, gtid);
        else phase5<false>(wih0, emb, condf, bias0f, base0, embW, gtid);
    }
    gbar_heavy(hcnt, hgen);  // L2 invalidated: cached reads see fresh staged data

    const bool headwg = (ut < 16);
    // ---------------- weight preload into 128 VGPRs (round-4-proven budget) ----------------
    // wA: phase-A weight hi (whh0 for mat0, whh1 for mat1)
    // wB: bf16 -> wih1-hi (mat1), wo1T head slice (head wave0), dup (others)
    //     fp32 -> lo-plane of wA's matrix
    bf16x8 wA[16], wB[16];
    {
        const u16* BhA = (mat == 0 ? W0hi : W1hi) + (size_t)(colb + n) * Hn;
        const u16* BhB;
        if (isbf) {
            if (mat == 1) BhB = Wi1hi + (size_t)(colb + n) * Hn;
            else if (headwg && wv == 0) BhB = wo1Th + (size_t)(ut * 16 + n) * Hn;
            else BhB = BhA;
        } else {
            BhB = (mat == 0 ? W0lo : W1lo) + (size_t)(colb + n) * Hn;
        }
#pragma unroll
        for (int it = 0; it < 16; ++it) {
            wA[it] = *(const bf16x8*)(BhA + it * 32 + q * 8);
            wB[it] = *(const bf16x8*)(BhB + it * 32 + q * 8);
        }
    }
    // head wo1T slice -> LDS (fp32 fallback only; bf16 path has it in wave0's wB regs)
    if (!isbf && headwg) {
        for (int e = tid; e < 16 * Hn; e += NTHR) {
            int col = e >> 9, k = e & 511;
            lwoh[col * LSTR + k] = wo1Th[(size_t)(ut * 16 + col) * Hn + k];
            lwol[col * LSTR + k] = wo1Tl[(size_t)(ut * 16 + col) * Hn + k];
        }
    }

    // ---------------- main loop ----------------
    float c0 = 0.f, c1 = 0.f;
    const int lr = tid >> 4;          // local row 0..15 (for tid<256)
    const int un = tid & 15;
    const int bb = R0g + lr;
    const int uu = ut * 16 + un;
    const float* bo1f = cpar + 2048;
    const float* bo2f = cpar + 2304;
    const float* wo2f = cpar + 3584;
    const int srow = tid >> 5;        // staging row 0..15
    const int blk = tid & 31;         // staging col-block == producer ut
    const int kub = blk * 16;         // staging u32 offset
    f32x4 acc1c = Z4;

    for (int e = tid; e < RPG * LSTR; e += NTHR) {
        lh0h[e] = 0; lh0l[e] = 0; lh1h[e] = 0; lh1l[e] = 0;
    }
    if (tid < 32) pvs[tid] = isbf ? bf2f(((const u16*)init_t)[tid & 1])
                                  : ((const float*)init_t)[tid & 1];

    // hoist loop-invariant gate operands into registers (gates threads only)
    float b0v[4], wpv[8], b1v[4];
    if (tid < 256) {
#pragma unroll
        for (int gi = 0; gi < 4; ++gi) {
            int cc = gi * 512 + uu;
            b0v[gi] = base0[(size_t)bb * G4 + cc];
            wpv[2 * gi] = wpb[2 * cc];
            wpv[2 * gi + 1] = wpb[2 * cc + 1];
            b1v[gi] = b1sum[cc];
        }
    }
    __syncthreads();  // lh* zero-init visible before t=0 early gemm

    for (int t = 0; t < Tn; ++t) {
        // ==== A: mat0 gemm EARLY (lh0 from prev phase B, barrier-separated);
        //         poll (wave7) overlaps; stage h1; head (wave0); whh1 (mat1);
        //         consume parts (wave4); gates0 ====
        if (mat == 0) {
            f32x4 a = isbf ? gemm16_regB2(lh0h, lh0l, wA, n, q)
                           : gemm16_regB3(lh0h, lh0l, wA, wB, n, q);
#pragma unroll
            for (int r = 0; r < 4; ++r)
                smemx[gw * 256 + (q * 4 + r) * 16 + n] = a[r];
        }
        // prefetch embW row for gates0 (plain cached loads; completed by next barrier)
        float ew0, ew1, ew2, ew3;
        if (tid < 256) {
            int id = char_ids[bb * Tn + t];
            const float* er = embW + (size_t)id * G4 + uu;
            ew0 = er[0]; ew1 = er[512]; ew2 = er[1024]; ew3 = er[1536];
        }
        if (t >= 1) {
            if (wv == 7) poll32(gf, 2 * (u32)t);  // overlaps mat0 gemms
            __syncthreads();
            if (blk != ut) {  // own block was written to LDS directly by gates1
                u32 w[16];
                cload16(h1p + (size_t)(R0g + srow) * Hn + kub, w);
                unpack16(w, lh1h + srow * LSTR + kub, lh1l + srow * LSTR + kub);
            }
        }
        __syncthreads();
        if (headwg && wv == 0 && t >= 1) {
            f32x4 ha = isbf ? gemm16_regB2(lh1h, lh1l, wB, n, q)
                            : gemm16_ldsB3(lh1h, lh1l, lwoh, lwol, n, q);
            float p[4][2];
#pragma unroll
            for (int r = 0; r < 4; ++r) {
                float hv = leaky(ha[r] + bo1f[ut * 16 + n]);
                p[r][0] = hv * wo2f[(ut * 16 + n) * 2];
                p[r][1] = hv * wo2f[(ut * 16 + n) * 2 + 1];
            }
#pragma unroll
            for (int r = 0; r < 4; ++r)
#pragma unroll
                for (int j = 0; j < 2; ++j) {
                    float s = p[r][j];
                    s += __shfl_xor(s, 1, 16);
                    s += __shfl_xor(s, 2, 16);
                    s += __shfl_xor(s, 4, 16);
                    s += __shfl_xor(s, 8, 16);
                    p[r][j] = s;
                }
            if (n == 0) {
#pragma unroll
                for (int r = 0; r < 4; ++r)
#pragma unroll
                    for (int j = 0; j < 2; ++j) {
                        int row = q * 4 + r;
                        cstore1((u32*)(part + (row * 2 + j) * 16 + ut), f2u(p[r][j]));
                    }
            }
            cwait();
            if (tid == 0) cstore1(gf2 + ut, (u32)t);
        }
        if (mat == 1) {
            acc1c = isbf ? gemm16_regB2(lh1h, lh1l, wA, n, q)
                         : gemm16_regB3(lh1h, lh1l, wA, wB, n, q);
        }
        if (t >= 1 && wv == 4) {
            // consume head partials on wave4: runs concurrent with wave0's head chain
            poll16(gf2, (u32)t);
            if (lane < 32) {
                int l = tid - 256;  // 0..31
                int row = l >> 1, j = l & 1;
                u32 hw[16];
                cload16((const u32*)(part + (row * 2 + j) * 16), hw);
                float s = bo2f[j];
#pragma unroll
                for (int i = 0; i < 16; ++i) s += u2f(hw[i]);
                float y = softplus(s) + 0.005f;
                pvs[row * 2 + j] = y;
                if (ut == 0) {
                    size_t oi = ((size_t)(R0g + row) * Tn + (t - 1)) * 2 + j;
                    if (isbf) ((u16*)outp)[oi] = f2bf(y);
                    else ((float*)outp)[oi] = y;
                }
            }
        }
        __syncthreads();
        if (tid < 256) {
            float pv0 = pvs[lr * 2], pv1 = pvs[lr * 2 + 1];
            float gv[4];
            gv[0] = smemx[0 * 256 + lr * 16 + un] + b0v[0] + ew0 + pv0 * wpv[0] + pv1 * wpv[1];
            gv[1] = smemx[1 * 256 + lr * 16 + un] + b0v[1] + ew1 + pv0 * wpv[2] + pv1 * wpv[3];
            gv[2] = smemx[2 * 256 + lr * 16 + un] + b0v[2] + ew2 + pv0 * wpv[4] + pv1 * wpv[5];
            gv[3] = smemx[3 * 256 + lr * 16 + un] + b0v[3] + ew3 + pv0 * wpv[6] + pv1 * wpv[7];
            float ig = sigm(gv[0]), fg = sigm(gv[1]), gg = tanhf(gv[2]), og = sigm(gv[3]);
            c0 = fg * c0 + ig * gg;
            float h = og * tanhf(c0);
            u16 hv = f2bf(h);
            u16 lv = f2bf(h - bf2f(hv));
            lh0h[lr * LSTR + uu] = hv;  // own block direct to LDS
            lh0l[lr * LSTR + uu] = lv;
            cstore1(h0p + (size_t)bb * Hn + uu, (u32)hv | ((u32)lv << 16));
        }
        cwait();
        __syncthreads();
        if (tid == 0) cstore1(gfl, 2 * (u32)t + 1);

        // ==== B: stage h0(t); wih1 GEMM (mat1 waves); gates1 -> h1(t) ====
        if (wv == 0) poll32(gf, 2 * (u32)t + 1);
        __syncthreads();
        if (blk != ut) {
            u32 w[16];
            cload16(h0p + (size_t)(R0g + srow) * Hn + kub, w);
            unpack16(w, lh0h + srow * LSTR + kub, lh0l + srow * LSTR + kub);
        }
        __syncthreads();
        if (mat == 1) {
            f32x4 a = isbf ? gemm16_s2(lh0h, lh0l, Wi1hi, colb, n, q)
                           : gemm16_3(lh0h, lh0l, Wi1hi, Wi1lo, colb, n, q);
            acc1c = acc1c + a;
#pragma unroll
            for (int r = 0; r < 4; ++r)
                smemx[gw * 256 + (q * 4 + r) * 16 + n] = acc1c[r];
        }
        __syncthreads();
        if (tid < 256) {
            float gv[4];
#pragma unroll
            for (int gi = 0; gi < 4; ++gi)
                gv[gi] = smemx[gi * 256 + lr * 16 + un] + b1v[gi];
            float ig = sigm(gv[0]), fg = sigm(gv[1]), gg = tanhf(gv[2]), og = sigm(gv[3]);
            c1 = fg * c1 + ig * gg;
            float h = og * tanhf(c1);
            u16 hv = f2bf(h);
            u16 lv = f2bf(h - bf2f(hv));
            lh1h[lr * LSTR + uu] = hv;  // own block direct to LDS
            lh1l[lr * LSTR + uu] = lv;
            cstore1(h1p + (size_t)bb * Hn + uu, (u32)hv | ((u32)lv << 16));
        }
        cwait();
        __syncthreads();
        if (tid == 0) cstore1(gfl, 2 * (u32)t + 2);
    }

    // ---------------- epilogue: head for t = 511 ----------------
    if (wv == 0) poll32(gf, 2 * (u32)Tn);
    __syncthreads();
    if (blk != ut) {
        u32 w[16];
        cload16(h1p + (size_t)(R0g + srow) * Hn + kub, w);
        unpack16(w, lh1h + srow * LSTR + kub, lh1l + srow * LSTR + kub);
    }
    __syncthreads();
    if (headwg && wv == 0) {
        f32x4 ha = isbf ? gemm16_regB2(lh1h, lh1l, wB, n, q)
                        : gemm16_ldsB3(lh1h, lh1l, lwoh, lwol, n, q);
        float p[4][2];
#pragma unroll
        for (int r = 0; r < 4; ++r) {
            float hv = leaky(ha[r] + bo1f[ut * 16 + n]);
            p[r][0] = hv * wo2f[(ut * 16 + n) * 2];
            p[r][1] = hv * wo2f[(ut * 16 + n) * 2 + 1];
        }
#pragma unroll
        for (int r = 0; r < 4; ++r)
#pragma unroll
            for (int j = 0; j < 2; ++j) {
                float s = p[r][j];
                s += __shfl_xor(s, 1, 16);
                s += __shfl_xor(s, 2, 16);
                s += __shfl_xor(s, 4, 16);
                s += __shfl_xor(s, 8, 16);
                p[r][j] = s;
            }
        if (n == 0) {
#pragma unroll
            for (int r = 0; r < 4; ++r)
#pragma unroll
                for (int j = 0; j < 2; ++j) {
                    int row = q * 4 + r;
                    cstore1((u32*)(part + (row * 2 + j) * 16 + ut), f2u(p[r][j]));
                }
        }
        cwait();
        if (tid == 0) cstore1(gf2 + ut, (u32)Tn);
    }
    if (ut == 0 && wv == 0) {
        poll16(gf2, (u32)Tn);
        if (tid < 32) {
            int row = tid >> 1, j = tid & 1;
            u32 hw[16];
            cload16((const u32*)(part + (row * 2 + j) * 16), hw);
            float s = bo2f[j];
#pragma unroll
            for (int i = 0; i < 16; ++i) s += u2f(hw[i]);
            float y = softplus(s) + 0.005f;
            size_t oi = ((size_t)(R0g + row) * Tn + (Tn - 1)) * 2 + j;
            if (isbf) ((u16*)outp)[oi] = f2bf(y);
            else ((float*)outp)[oi] = y;
        }
    }
}

extern "C" void kernel_launch(void* const* d_in, const int* in_sizes, int n_in,
                              void* d_out, int out_size, void* d_ws, size_t ws_size,
                              hipStream_t stream) {
    (void)in_sizes; (void)n_in; (void)out_size; (void)ws_size;
    init_flags_kernel<<<1, 1024, 0, stream>>>((int*)d_ws);
    gen_kernel<<<WGS, NTHR, 0, stream>>>(
        (const int*)d_in[0], d_in[1], d_in[2], d_in[3], d_in[4], d_in[5], d_in[6], d_in[7],
        d_in[8], d_in[9], d_in[10], d_in[11], d_in[12], d_in[13], d_in[14], d_in[15], d_in[16],
        d_in[17], d_in[18], d_in[19], d_in[20], d_in[21], d_in[22], d_in[23],
        d_out, (char*)d_ws);
}